// Round 1
// baseline (946.185 us; speedup 1.0000x reference)
//
#include <hip/hip_runtime.h>

static constexpr int D = 8;
static constexpr int B = 16;
static constexpr int N = 2048;
static constexpr float ALPHA = 0.95122945f;   // == ALPHA_P == ALPHA_D

// Main kernel: per (e, o-half) block, loop b inside so dmap/A_p/A_d are
// fetched from HBM exactly once. out = W is fused with the W read.
__global__ __launch_bounds__(256) void stdp_main_kernel(
    const float* __restrict__ Xd,         // (D,B,N)
    const float* __restrict__ Xpost,      // (B,N)
    const float* __restrict__ xbar_pre,   // (D,B,N)
    const float* __restrict__ xbar_post,  // (B,N)
    const float* __restrict__ W,          // (B,N,N)
    const float* __restrict__ A_p,        // (N,N)
    const float* __restrict__ A_d,        // (N,N)
    const float* __restrict__ dmap,       // (D,N,N)
    float* __restrict__ out,              // (B,N,N)
    float* __restrict__ W_new)            // (B,N,N)
{
    const int e = blockIdx.x;                              // pre index
    const int o = (blockIdx.y << 10) + (threadIdx.x << 2); // post index (float4)

    // Per-e traces, shared by all threads of the block (broadcast reads -> no
    // bank conflicts: all lanes read the same [d][b] address).
    __shared__ float s_pre[D][B];
    __shared__ float s_xd[D][B];
    {
        const int t = threadIdx.x;
        if (t < D * B) {
            const int d = t >> 4, b = t & (B - 1);
            s_pre[d][b] = xbar_pre[(d * B + b) * N + e];
        } else if (t < 2 * D * B) {
            const int tt = t - D * B;
            const int d = tt >> 4, b = tt & (B - 1);
            s_xd[d][b] = Xd[(d * B + b) * N + e];
        }
    }
    __syncthreads();

    // dmap fragment for this (e, o..o+3): 8 x float4 = 32 VGPRs, read once.
    float4 dm[D];
#pragma unroll
    for (int d = 0; d < D; ++d)
        dm[d] = *reinterpret_cast<const float4*>(dmap + ((size_t)(d * N + e) * N + o));

    const float4 ap = *reinterpret_cast<const float4*>(A_p + ((size_t)e * N + o));
    const float4 ad = *reinterpret_cast<const float4*>(A_d + ((size_t)e * N + o));

#pragma unroll 4
    for (int b = 0; b < B; ++b) {
        const size_t widx = ((size_t)b * N + e) * N + o;
        const float4 w   = *reinterpret_cast<const float4*>(W + widx);
        const float4 xp  = *reinterpret_cast<const float4*>(Xpost + (b * N + o));
        const float4 xbp = *reinterpret_cast<const float4*>(xbar_post + (b * N + o));

        // s1 = sum_d dmap[d,e,o] * xbar_pre[d,b,e]
        // s2 = sum_d dmap[d,e,o] * Xd[d,b,e]
        float4 s1 = make_float4(0.f, 0.f, 0.f, 0.f);
        float4 s2 = make_float4(0.f, 0.f, 0.f, 0.f);
#pragma unroll
        for (int d = 0; d < D; ++d) {
            const float pre = s_pre[d][b];
            const float xd  = s_xd[d][b];
            s1.x = fmaf(dm[d].x, pre, s1.x);
            s1.y = fmaf(dm[d].y, pre, s1.y);
            s1.z = fmaf(dm[d].z, pre, s1.z);
            s1.w = fmaf(dm[d].w, pre, s1.w);
            s2.x = fmaf(dm[d].x, xd, s2.x);
            s2.y = fmaf(dm[d].y, xd, s2.y);
            s2.z = fmaf(dm[d].z, xd, s2.z);
            s2.w = fmaf(dm[d].w, xd, s2.w);
        }

        float4 wn;
        wn.x = w.x + xp.x * ap.x * s1.x - xbp.x * ad.x * s2.x;
        wn.y = w.y + xp.y * ap.y * s1.y - xbp.y * ad.y * s2.y;
        wn.z = w.z + xp.z * ap.z * s1.z - xbp.z * ad.z * s2.z;
        wn.w = w.w + xp.w * ap.w * s1.w - xbp.w * ad.w * s2.w;
        wn.x = fminf(fmaxf(wn.x, 0.f), 1.f);
        wn.y = fminf(fmaxf(wn.y, 0.f), 1.f);
        wn.z = fminf(fmaxf(wn.z, 0.f), 1.f);
        wn.w = fminf(fmaxf(wn.w, 0.f), 1.f);

        *reinterpret_cast<float4*>(out + widx)   = w;   // out = W (pre-update)
        *reinterpret_cast<float4*>(W_new + widx) = wn;
    }
}

// Trace updates: xbar_new = alpha*xbar + (1-alpha)*x   (both alphas equal)
__global__ __launch_bounds__(256) void expfilt_kernel(
    const float* __restrict__ Xd,
    const float* __restrict__ Xpost,
    const float* __restrict__ xbar_pre,
    const float* __restrict__ xbar_post,
    float* __restrict__ xbar_pre_new,
    float* __restrict__ xbar_post_new)
{
    const int n_pre4  = D * B * N / 4;  // 65536
    const int n_post4 = B * N / 4;      // 8192
    const float beta = 1.0f - ALPHA;
    const int i = blockIdx.x * blockDim.x + threadIdx.x;
    if (i < n_pre4) {
        const float4 xb = reinterpret_cast<const float4*>(xbar_pre)[i];
        const float4 x  = reinterpret_cast<const float4*>(Xd)[i];
        float4 r;
        r.x = fmaf(ALPHA, xb.x, beta * x.x);
        r.y = fmaf(ALPHA, xb.y, beta * x.y);
        r.z = fmaf(ALPHA, xb.z, beta * x.z);
        r.w = fmaf(ALPHA, xb.w, beta * x.w);
        reinterpret_cast<float4*>(xbar_pre_new)[i] = r;
    } else {
        const int j = i - n_pre4;
        if (j < n_post4) {
            const float4 xb = reinterpret_cast<const float4*>(xbar_post)[j];
            const float4 x  = reinterpret_cast<const float4*>(Xpost)[j];
            float4 r;
            r.x = fmaf(ALPHA, xb.x, beta * x.x);
            r.y = fmaf(ALPHA, xb.y, beta * x.y);
            r.z = fmaf(ALPHA, xb.z, beta * x.z);
            r.w = fmaf(ALPHA, xb.w, beta * x.w);
            reinterpret_cast<float4*>(xbar_post_new)[j] = r;
        }
    }
}

extern "C" void kernel_launch(void* const* d_in, const int* in_sizes, int n_in,
                              void* d_out, int out_size, void* d_ws, size_t ws_size,
                              hipStream_t stream) {
    const float* Xd        = (const float*)d_in[0];
    const float* Xpost     = (const float*)d_in[1];
    const float* xbar_pre  = (const float*)d_in[2];
    const float* xbar_post = (const float*)d_in[3];
    const float* W         = (const float*)d_in[4];
    const float* A_p       = (const float*)d_in[5];
    const float* A_d       = (const float*)d_in[6];
    const float* dmap      = (const float*)d_in[7];

    float* out           = (float*)d_out;                       // (B,N,N)
    float* W_new         = out + (size_t)B * N * N;             // (B,N,N)
    float* xbar_pre_new  = W_new + (size_t)B * N * N;           // (D,B,N)
    float* xbar_post_new = xbar_pre_new + (size_t)D * B * N;    // (B,N)

    dim3 grid(N, 2);  // 2048 e-rows x 2 o-halves = 4096 blocks (16/CU)
    stdp_main_kernel<<<grid, 256, 0, stream>>>(
        Xd, Xpost, xbar_pre, xbar_post, W, A_p, A_d, dmap, out, W_new);

    const int total4 = (D * B * N + B * N) / 4;  // 73728 -> 288 blocks
    expfilt_kernel<<<(total4 + 255) / 256, 256, 0, stream>>>(
        Xd, Xpost, xbar_pre, xbar_post, xbar_pre_new, xbar_post_new);
}